// Round 6
// baseline (460.909 us; speedup 1.0000x reference)
//
#include <hip/hip_runtime.h>

// Problem constants (fixed by setup_inputs)
constexpr int NPTS = 16384;
constexpr int KNB  = 9;
constexpr int CDIM = 16;
constexpr int HDIM = 32;

// Spatial grid: FIXED bounds (data ~ N(0,1)). Outliers clamp into edge cells;
// search stays EXACT: edge cells own all points beyond the boundary, and a
// clipped side contributes no uncovered region (FBIG) once the block reaches
// the grid edge.
constexpr int   G    = 128;
constexpr int   GC   = G * G;            // 16384 cells
constexpr float GMIN = -3.3f;
constexpr float GMAX =  3.3f;
constexpr float CW   = (GMAX - GMIN) / G;
constexpr float INVW = G / (GMAX - GMIN);
constexpr float FBIG = 3.0e38f;

constexpr int RCAP = 5;                  // ring cap; ~2% of points overflow
                                         // to the brute-force straggler pass

// ---------------------------------------------------------------------------
// Register-resident top-9 (smallest d2). Arrays indexed only with
// compile-time constants -> stay in VGPRs.
// ---------------------------------------------------------------------------
struct TopK {
    float d[KNB];
    int   id[KNB];
    float dw;

    __device__ __forceinline__ void init() {
#pragma unroll
        for (int s = 0; s < KNB; ++s) { d[s] = FBIG; id[s] = -1; }
        dw = FBIG;
    }
    __device__ __forceinline__ void push(float d2, int j) {
        if (d2 < dw) {
            bool done = false;
#pragma unroll
            for (int s = 0; s < KNB; ++s) {
                bool m = (!done) && (d[s] == dw);
                d[s]  = m ? d2 : d[s];
                id[s] = m ? j  : id[s];
                done  = done || m;
            }
            float m0 = fmaxf(fmaxf(d[0], d[1]), d[2]);
            float m1 = fmaxf(fmaxf(d[3], d[4]), d[5]);
            float m2 = fmaxf(fmaxf(d[6], d[7]), d[8]);
            dw = fmaxf(fmaxf(m0, m1), m2);
        }
    }
};

__device__ __forceinline__ int clampG(int c) { return min(G - 1, max(0, c)); }

// ---------------------------------------------------------------------------
// Fused bin-count + exclusive-scan + scatter, ONE block of 1024 threads.
// LDS histogram (64 KB) -> in-LDS scan -> LDS-cursor scatter. Each thread
// owns 16 points (interleaved t, t+1024, ... for coalesced loads) and 16
// cells [16t, 16t+16) for the scan. Also zeroes scnt (no memsets anywhere).
// Replaces 3 dispatches + 1 memset per step with 1 dispatch.
// ---------------------------------------------------------------------------
__global__ __launch_bounds__(1024) void prep(const float* __restrict__ x,
                                             unsigned short* __restrict__ cs16,
                                             float2* __restrict__ bxy,
                                             int* __restrict__ bid,
                                             int* __restrict__ scnt) {
    __shared__ int hist[GC];             // 64 KB: counts -> cellStart -> cursor
    __shared__ int wsum[16];

    const int t    = threadIdx.x;
    const int lane = t & 63;
    const int wid  = t >> 6;

#pragma unroll
    for (int k = 0; k < GC / 1024; ++k) hist[t + 1024 * k] = 0;
    if (t == 0) scnt[0] = 0;
    __syncthreads();

    // ---- count (and stash each point's cell/coords in registers) ----
    int    myc[16];
    float2 myp[16];
#pragma unroll
    for (int k = 0; k < 16; ++k) {
        const int i = t + 1024 * k;
        const float2 p = *reinterpret_cast<const float2*>(x + (size_t)i * CDIM);
        const int cx = clampG((int)((p.x - GMIN) * INVW));
        const int cy = clampG((int)((p.y - GMIN) * INVW));
        const int c = cy * G + cx;
        myp[k] = p;
        myc[k] = c;
        atomicAdd(&hist[c], 1);
    }
    __syncthreads();

    // ---- exclusive scan over 16384 cells ----
    int loc[16];
    int sum = 0;
    const int base = t * 16;
#pragma unroll
    for (int k = 0; k < 16; ++k) { loc[k] = sum; sum += hist[base + k]; }

    int inc = sum;
#pragma unroll
    for (int o = 1; o < 64; o <<= 1) {
        const int v = __shfl_up(inc, o);
        if (lane >= o) inc += v;
    }
    if (lane == 63) wsum[wid] = inc;
    __syncthreads();
    int woff = 0;
    for (int i = 0; i < 16; ++i) woff += (i < wid) ? wsum[i] : 0;
    const int excl = woff + inc - sum;

#pragma unroll
    for (int k = 0; k < 16; ++k) {
        const int v = excl + loc[k];
        hist[base + k] = v;                       // becomes the cursor
        cs16[base + k] = (unsigned short)v;       // span table for knn
    }
    if (t == 1023) { cs16[GC] = (unsigned short)NPTS; cs16[GC + 1] = (unsigned short)NPTS; }
    __syncthreads();

    // ---- scatter into binned order ----
#pragma unroll
    for (int k = 0; k < 16; ++k) {
        const int pos = atomicAdd(&hist[myc[k]], 1);
        bxy[pos] = myp[k];
        bid[pos] = t + 1024 * k;
    }
}

// ---------------------------------------------------------------------------
// Exact capped kNN, one lane per point (lane-local top-9 == exact union, so
// the ring stop-bound fires at the true 9-NN radius). Binned-order lanes are
// spatially coherent -> per-wave divergence ~ max span. Points not converged
// by ring RCAP go to the straggler list. Prologue also re-orders the feature
// rows into binned order (xb) — hides under the LDS span-table load.
// 64 blocks x 256 threads.
// ---------------------------------------------------------------------------
__global__ __launch_bounds__(256) void knn_search(const float2* __restrict__ bxy,
                                                  const unsigned short* __restrict__ cs16,
                                                  const int* __restrict__ bid,
                                                  const float* __restrict__ xin,
                                                  float* __restrict__ xb,
                                                  int* __restrict__ nb,
                                                  int* __restrict__ scnt,
                                                  int* __restrict__ slist) {
    __shared__ unsigned short sCS[GC + 2];

    const int p = blockIdx.x * 256 + threadIdx.x;

    // feature re-order: xb[p] = xin[bid[p]]  (gathered read, coalesced write)
    {
        const float4* src = reinterpret_cast<const float4*>(xin + (size_t)bid[p] * CDIM);
        float4* dst = reinterpret_cast<float4*>(xb + (size_t)p * CDIM);
        dst[0] = src[0]; dst[1] = src[1]; dst[2] = src[2]; dst[3] = src[3];
    }

    {
        const uint* src = reinterpret_cast<const uint*>(cs16);
        uint* dst = reinterpret_cast<uint*>(sCS);
        for (int t = threadIdx.x; t < (GC + 2) / 2; t += 256) dst[t] = src[t];
    }
    __syncthreads();

    const float2 q = bxy[p];
    const float qx = q.x, qy = q.y;
    const int cx = clampG((int)((qx - GMIN) * INVW));
    const int cy = clampG((int)((qy - GMIN) * INVW));

    TopK tk; tk.init();

    auto scan_span = [&](int s, int e) {
        for (int i = s; i < e; ++i) {
            const float2 pt = bxy[i];
            const float dx = qx - pt.x;
            const float dy = qy - pt.y;
            tk.push(fmaf(dx, dx, dy * dy), i);
        }
    };
    auto row_span = [&](int y, int x0, int x1) {
        if (y < 0 || y >= G) return;
        x0 = max(x0, 0); x1 = min(x1, G - 1);
        if (x0 > x1) return;
        scan_span((int)sCS[y * G + x0], (int)sCS[y * G + x1 + 1]);
    };

    row_span(cy - 1, cx - 1, cx + 1);
    row_span(cy,     cx - 1, cx + 1);
    row_span(cy + 1, cx - 1, cx + 1);

    bool done = false;
    int r = 1;
    while (true) {
        const float dl = (cx - r >= 0) ? fmaxf(qx - (GMIN + (float)(cx - r) * CW), 0.0f) : FBIG;
        const float dr = (cx + r <  G) ? fmaxf((GMIN + (float)(cx + r + 1) * CW) - qx, 0.0f) : FBIG;
        const float db = (cy - r >= 0) ? fmaxf(qy - (GMIN + (float)(cy - r) * CW), 0.0f) : FBIG;
        const float dt = (cy + r <  G) ? fmaxf((GMIN + (float)(cy + r + 1) * CW) - qy, 0.0f) : FBIG;
        const float dmin = fminf(fminf(dl, dr), fminf(db, dt));
        if (tk.dw < FBIG && tk.dw <= dmin * dmin) { done = true; break; }
        if (r == RCAP) break;
        ++r;
        row_span(cy - r, cx - r, cx + r);
        row_span(cy + r, cx - r, cx + r);
        for (int y = cy - r + 1; y <= cy + r - 1; ++y) {
            if (y < 0 || y >= G) continue;
            if (cx - r >= 0) scan_span((int)sCS[y * G + cx - r], (int)sCS[y * G + cx - r + 1]);
            if (cx + r <  G) scan_span((int)sCS[y * G + cx + r], (int)sCS[y * G + cx + r + 1]);
        }
    }

    if (done) {
#pragma unroll
        for (int s = 0; s < KNB; ++s) nb[p * KNB + s] = tk.id[s];
    } else {
        const int slot = atomicAdd(scnt, 1);
        slist[slot] = p;
    }
}

// ---------------------------------------------------------------------------
// Straggler pass: one 64-lane wave per straggler, brute force over all 16384
// candidates via float4 loads (2 pts/load, unrolled -> 4 independent loads in
// flight; issue-bound, not latency-bound). 256 blocks x 256 threads = 1024
// waves >= any plausible straggler count (grid-stride kept for safety).
// ---------------------------------------------------------------------------
__global__ __launch_bounds__(256) void knn_brute(const float2* __restrict__ bxy,
                                                 const int* __restrict__ scnt,
                                                 const int* __restrict__ slist,
                                                 int* __restrict__ nb) {
    const int lane   = threadIdx.x & 63;
    const int wave   = (blockIdx.x * 256 + threadIdx.x) >> 6;
    const int nwaves = (gridDim.x * 256) >> 6;
    const int n = scnt[0];
    const float4* bf4 = reinterpret_cast<const float4*>(bxy);

    for (int w = wave; w < n; w += nwaves) {
        const int p = slist[w];
        const float2 q = bxy[p];
        TopK tk; tk.init();
#pragma unroll 2
        for (int k = 0; k < NPTS / 128; ++k) {
            const int i4 = lane + 64 * k;           // covers points 2*i4, 2*i4+1
            const float4 v = bf4[i4];
            const float dx0 = q.x - v.x, dy0 = q.y - v.y;
            const float dx1 = q.x - v.z, dy1 = q.y - v.w;
            tk.push(fmaf(dx0, dx0, dy0 * dy0), 2 * i4);
            tk.push(fmaf(dx1, dx1, dy1 * dy1), 2 * i4 + 1);
        }
#pragma unroll
        for (int m = 1; m < 64; m <<= 1) {
            float od[KNB]; int oid[KNB];
#pragma unroll
            for (int s = 0; s < KNB; ++s) {
                od[s]  = __shfl_xor(tk.d[s], m);
                oid[s] = __shfl_xor(tk.id[s], m);
            }
#pragma unroll
            for (int s = 0; s < KNB; ++s) tk.push(od[s], oid[s]);
        }
        if (lane == 0) {
#pragma unroll
            for (int s = 0; s < KNB; ++s) nb[p * KNB + s] = tk.id[s];
        }
    }
}

// ---------------------------------------------------------------------------
// GCN layer in binned order, thread per point, 64 blocks x 256 threads.
// FINAL fuses residual and scatters back to original order via bid.
// ---------------------------------------------------------------------------
template <int CIN, int COUT, bool RELU, bool FINAL>
__global__ __launch_bounds__(256) void gcn_layer(const float* __restrict__ hin,
                                                 const int* __restrict__ nb,
                                                 const float* __restrict__ W,
                                                 const float* __restrict__ xb,
                                                 const int* __restrict__ bid,
                                                 float* __restrict__ hout) {
    const int n = blockIdx.x * 256 + threadIdx.x;

    float agg[CIN];
#pragma unroll
    for (int c = 0; c < CIN; ++c) agg[c] = 0.0f;

#pragma unroll
    for (int k = 0; k < KNB; ++k) {
        const int j = nb[n * KNB + k];
        const float4* r = reinterpret_cast<const float4*>(hin + (size_t)j * CIN);
#pragma unroll
        for (int c4 = 0; c4 < CIN / 4; ++c4) {
            const float4 v = r[c4];
            agg[4 * c4 + 0] += v.x;
            agg[4 * c4 + 1] += v.y;
            agg[4 * c4 + 2] += v.z;
            agg[4 * c4 + 3] += v.w;
        }
    }
#pragma unroll
    for (int c = 0; c < CIN; ++c) agg[c] *= (1.0f / 9.0f);

    const int outrow = FINAL ? bid[n] : n;
#pragma unroll
    for (int o = 0; o < COUT; ++o) {
        float acc = 0.0f;
#pragma unroll
        for (int c = 0; c < CIN; ++c) acc = fmaf(agg[c], W[c * COUT + o], acc);
        if (RELU)  acc = fmaxf(acc, 0.0f);
        if (FINAL) acc = xb[n * COUT + o] + 1e-4f * acc;
        hout[outrow * COUT + o] = acc;
    }
}

// ---------------------------------------------------------------------------
// 2 fixed steps x 7 dispatches: prep, knn_search, knn_brute, 4x gcn_layer.
// ---------------------------------------------------------------------------
extern "C" void kernel_launch(void* const* d_in, const int* in_sizes, int n_in,
                              void* d_out, int out_size, void* d_ws, size_t ws_size,
                              hipStream_t stream) {
    const float* seed = (const float*)d_in[0];
    const float* W1   = (const float*)d_in[1];
    const float* W2   = (const float*)d_in[2];
    const float* W3   = (const float*)d_in[3];
    const float* W4   = (const float*)d_in[4];
    float* out = (float*)d_out;

    char* ws = (char*)d_ws;
    size_t off = 0;
    auto alloc = [&](size_t bytes) -> void* {
        void* p = ws + off;
        off += (bytes + 255) & ~(size_t)255;
        return p;
    };
    unsigned short* cs16  = (unsigned short*)alloc((GC + 2) * sizeof(unsigned short));
    float2*         bxy   = (float2*)alloc((size_t)NPTS * sizeof(float2));
    int*            bid   = (int*)   alloc(NPTS * sizeof(int));
    float*          xb    = (float*) alloc((size_t)NPTS * CDIM * sizeof(float));
    int*            nb    = (int*)   alloc((size_t)NPTS * KNB * sizeof(int));
    float*          hA    = (float*) alloc((size_t)NPTS * HDIM * sizeof(float));
    float*          hB    = (float*) alloc((size_t)NPTS * HDIM * sizeof(float));
    float*          x1    = (float*) alloc((size_t)NPTS * CDIM * sizeof(float));
    int*            scnt  = (int*)   alloc(256);
    int*            slist = (int*)   alloc(NPTS * sizeof(int));

    for (int step = 0; step < 2; ++step) {
        const float* xin  = (step == 0) ? seed : x1;
        float*       xout = (step == 0) ? x1   : out;

        prep      <<<1, 1024, 0, stream>>>(xin, cs16, bxy, bid, scnt);
        knn_search<<<64, 256, 0, stream>>>(bxy, cs16, bid, xin, xb, nb, scnt, slist);
        knn_brute <<<256, 256, 0, stream>>>(bxy, scnt, slist, nb);

        gcn_layer<CDIM, HDIM, true,  false><<<64, 256, 0, stream>>>(xb, nb, W1, nullptr, nullptr, hA);
        gcn_layer<HDIM, HDIM, true,  false><<<64, 256, 0, stream>>>(hA, nb, W2, nullptr, nullptr, hB);
        gcn_layer<HDIM, HDIM, true,  false><<<64, 256, 0, stream>>>(hB, nb, W3, nullptr, nullptr, hA);
        gcn_layer<HDIM, CDIM, false, true ><<<64, 256, 0, stream>>>(hA, nb, W4, xb, bid, xout);
    }
}